// Round 9
// baseline (70.192 us; speedup 1.0000x reference)
//
#include <hip/hip_runtime.h>
#include <hip/hip_bf16.h>

#define B_ROWS 8192
#define E_DIM  1024
#define MARGIN 0.2f

#define BM 128
#define BN 128
#define BK 32
#define KSPLIT 2
#define KHALF (E_DIM / KSPLIT)   // 512
#define NSTEPS (KHALF / BK)      // 16

typedef __bf16 bf16x8 __attribute__((ext_vector_type(8)));
typedef __bf16 bf16x4 __attribute__((ext_vector_type(4)));
typedef float  f32x4  __attribute__((ext_vector_type(4)));

__device__ __forceinline__ void gload_lds16(const void* g, void* l) {
    __builtin_amdgcn_global_load_lds(
        (__attribute__((address_space(1))) void*)(g),
        (__attribute__((address_space(3))) void*)(l),
        16, 0, 0);
}

#define GATE4() do { asm volatile("s_waitcnt vmcnt(4)" ::: "memory"); \
                     __builtin_amdgcn_sched_barrier(0); } while (0)
#define GATE0() do { asm volatile("s_waitcnt vmcnt(0)" ::: "memory"); \
                     __builtin_amdgcn_sched_barrier(0); } while (0)
#define RBAR()  do { __builtin_amdgcn_s_barrier(); \
                     __builtin_amdgcn_sched_barrier(0); } while (0)
#define LGKM0() do { asm volatile("s_waitcnt lgkmcnt(0)" ::: "memory"); \
                     __builtin_amdgcn_sched_barrier(0); } while (0)

// Combined prep: blocks [0,4096) c = 0.4*m + 0.6*tr_m; [4096,5120) W -> Wt.
__global__ __launch_bounds__(256)
void prep_combo(const float* __restrict__ m, const float* __restrict__ trm,
                __bf16* __restrict__ c,
                const float* __restrict__ W, __bf16* __restrict__ Wt) {
    __shared__ float tile[32][33];
    if (blockIdx.x < 4096) {
        size_t i = ((size_t)blockIdx.x * blockDim.x + threadIdx.x) * 8;
        float4 m0 = *(const float4*)(m + i);
        float4 m1 = *(const float4*)(m + i + 4);
        float4 t0 = *(const float4*)(trm + i);
        float4 t1 = *(const float4*)(trm + i + 4);
        bf16x8 v;
        v[0] = (__bf16)(0.4f*m0.x + 0.6f*t0.x);
        v[1] = (__bf16)(0.4f*m0.y + 0.6f*t0.y);
        v[2] = (__bf16)(0.4f*m0.z + 0.6f*t0.z);
        v[3] = (__bf16)(0.4f*m0.w + 0.6f*t0.w);
        v[4] = (__bf16)(0.4f*m1.x + 0.6f*t1.x);
        v[5] = (__bf16)(0.4f*m1.y + 0.6f*t1.y);
        v[6] = (__bf16)(0.4f*m1.z + 0.6f*t1.z);
        v[7] = (__bf16)(0.4f*m1.w + 0.6f*t1.w);
        *(bf16x8*)(c + i) = v;
    } else {
        const int tb = blockIdx.x - 4096;
        const int bx = (tb & 31) * 32;          // n base
        const int by = (tb >> 5) * 32;          // e base
        const int tx = threadIdx.x & 31;
        const int ty0 = threadIdx.x >> 5;
#pragma unroll
        for (int r = 0; r < 32; r += 8)
            tile[r + ty0][tx] = W[(size_t)(by + r + ty0) * E_DIM + bx + tx];
        __syncthreads();
#pragma unroll
        for (int r = 0; r < 32; r += 8)
            Wt[(size_t)(bx + r + ty0) * E_DIM + by + tx] = (__bf16)tile[tx][r + ty0];
    }
}

// K-loop: R8's ring-of-3 + counted vmcnt (unchanged, equal-best).
// NEW epilogue: acc -> u_lds bf16 [128][128] (aliased on staging LDS),
// then fully-coalesced float4 streaming dot with (Ais - Aem),
// 32-lane segmented reduce, one atomicAdd per row per block.
// Split-K=2 -> 1024 blocks, 48 KiB LDS -> 3 blocks/CU: late blocks'
// K-loops overlap early blocks' epilogues.
__global__ __launch_bounds__(256)
void gemm_dot(const __bf16* __restrict__ Cm, const __bf16* __restrict__ Wt,
              const float* __restrict__ Ais, const float* __restrict__ Aem,
              float* __restrict__ delta) {
    __shared__ char smem[49152];           // 3xA(8K) + 3xB(8K); epilogue: u 32K
    __bf16* Asb = (__bf16*)smem;           // slot*4096 elems
    __bf16* Bsb = (__bf16*)(smem + 24576);

    const int tid  = threadIdx.x;
    const int lane = tid & 63;
    const int wave = tid >> 6;
    const int lr   = lane & 15;
    const int hi   = lane >> 4;
    const int wr   = wave >> 1, wc = wave & 1;

    // 1024 blocks = 8 xcd x (colb:8, ks:2, pw:8). XCD owns 8 panels ->
    // L2 set: 8 c-panels (2 MiB) + Wt (2 MiB) + dA tiles.
    const int bid = blockIdx.x;
    const int xcd = bid & 7;
    const int q   = bid >> 3;            // 0..127
    const int rb    = (xcd * 8 + (q >> 4)) * BM;
    const int cb    = (q & 7) * BN;
    const int kbase = ((q >> 3) & 1) * KHALF;

    auto stage = [&](int slot, int k0) {
#pragma unroll
        for (int i = 0; i < 2; ++i) {
            int off = i * 4096 + tid * 16;
            int row = off >> 6;              // 64 B per 32-bf16 row
            int kb  = off & 63;
            gload_lds16((const char*)Cm + ((size_t)(rb + row) * E_DIM + k0) * 2 + kb,
                        smem + slot * 8192 + off);
            gload_lds16((const char*)Wt + ((size_t)(cb + row) * E_DIM + k0) * 2 + kb,
                        smem + 24576 + slot * 8192 + off);
        }
    };

    f32x4 acc[4][4] = {};

    stage(0, kbase);
    stage(1, kbase + BK);

    int s0 = 0, s1 = 1, s2 = 2;
    for (int t = 0; t < NSTEPS; ++t) {
        if (t + 1 < NSTEPS) GATE4(); else GATE0();
        RBAR();

        bf16x8 a[4], b[4];
#pragma unroll
        for (int mi = 0; mi < 4; ++mi)
            a[mi] = *(const bf16x8*)(&Asb[s0 * 4096 + (wr * 64 + mi * 16 + lr) * BK + hi * 8]);
#pragma unroll
        for (int ni = 0; ni < 4; ++ni)
            b[ni] = *(const bf16x8*)(&Bsb[s0 * 4096 + (wc * 64 + ni * 16 + lr) * BK + hi * 8]);
        LGKM0();

        if (t + 2 < NSTEPS) stage(s2, kbase + (t + 2) * BK);

        __builtin_amdgcn_s_setprio(1);
#pragma unroll
        for (int mi = 0; mi < 4; ++mi)
#pragma unroll
            for (int ni = 0; ni < 4; ++ni)
                acc[mi][ni] = __builtin_amdgcn_mfma_f32_16x16x32_bf16(
                    a[mi], b[ni], acc[mi][ni], 0, 0, 0);
        __builtin_amdgcn_s_setprio(0);

        int tmp = s0; s0 = s1; s1 = s2; s2 = tmp;
    }

    // ---- epilogue ----
    __syncthreads();   // everyone done reading staging LDS
    __bf16* u_lds = (__bf16*)smem;   // [128][128] bf16, 32 KiB

    // acc -> u_lds. C/D layout: col = lane&15, row = (lane>>4)*4 + reg
    const int rloc0 = wr * 64 + hi * 4;
    const int cloc0 = wc * 64 + lr;
#pragma unroll
    for (int mi = 0; mi < 4; ++mi)
#pragma unroll
        for (int jj = 0; jj < 4; ++jj) {
            __bf16* row = u_lds + (rloc0 + mi * 16 + jj) * 128 + cloc0;
#pragma unroll
            for (int ni = 0; ni < 4; ++ni)
                row[ni * 16] = (__bf16)acc[mi][ni][jj];
        }
    __syncthreads();

    // coalesced stream: half-wave (32 lanes) covers one row's 128 cols
    const int half = lane >> 5;       // 0/1
    const int cloc = (lane & 31) * 4;
#pragma unroll 4
    for (int it = 0; it < 16; ++it) {
        const int rloc = wave * 32 + it * 2 + half;
        const size_t gidx = (size_t)(rb + rloc) * E_DIM + cb + cloc;
        const float4 ai = *(const float4*)(Ais + gidx);
        const float4 ae = *(const float4*)(Aem + gidx);
        const bf16x4 u4 = *(const bf16x4*)(u_lds + rloc * 128 + cloc);
        float s = (float)u4[0] * (ai.x - ae.x)
                + (float)u4[1] * (ai.y - ae.y)
                + (float)u4[2] * (ai.z - ae.z)
                + (float)u4[3] * (ai.w - ae.w);
        s += __shfl_xor(s, 1);
        s += __shfl_xor(s, 2);
        s += __shfl_xor(s, 4);
        s += __shfl_xor(s, 8);
        s += __shfl_xor(s, 16);
        if ((lane & 31) == 0) atomicAdd(&delta[rb + rloc], s);
    }
}

__global__ void hinge_sum(const float* __restrict__ delta, float* __restrict__ out) {
    float s = 0.f;
    for (int i = threadIdx.x; i < B_ROWS; i += 256)
        s += fmaxf(MARGIN + delta[i], 0.f);
#pragma unroll
    for (int off = 32; off > 0; off >>= 1) s += __shfl_down(s, off);
    __shared__ float wsum[4];
    int lane = threadIdx.x & 63, w = threadIdx.x >> 6;
    if (lane == 0) wsum[w] = s;
    __syncthreads();
    if (threadIdx.x == 0) out[0] = wsum[0] + wsum[1] + wsum[2] + wsum[3];
}

extern "C" void kernel_launch(void* const* d_in, const int* in_sizes, int n_in,
                              void* d_out, int out_size, void* d_ws, size_t ws_size,
                              hipStream_t stream) {
    const float* A_is = (const float*)d_in[0];
    const float* A_em = (const float*)d_in[1];
    const float* m    = (const float*)d_in[2];
    const float* tr_m = (const float*)d_in[3];
    const float* W    = (const float*)d_in[4];
    // d_in[5] = b : cancels in diag_is - diag_em, unused.
    float* out = (float*)d_out;

    char* ws = (char*)d_ws;
    __bf16* c     = (__bf16*)ws;                              // 16 MiB
    __bf16* wt    = (__bf16*)(ws + (size_t)16 * 1024 * 1024); //  2 MiB
    float*  delta = (float*) (ws + (size_t)18 * 1024 * 1024); // 32 KiB

    hipMemsetAsync(delta, 0, B_ROWS * sizeof(float), stream);
    prep_combo<<<5120, 256, 0, stream>>>(m, tr_m, c, W, wt);
    gemm_dot<<<1024, 256, 0, stream>>>(c, wt, A_is, A_em, delta);
    hinge_sum<<<1, 256, 0, stream>>>(delta, out);
}